// Round 1
// baseline (1632.033 us; speedup 1.0000x reference)
//
#include <hip/hip_runtime.h>
#include <hip/hip_bf16.h>

// Problem constants
#define BATCH 16
#define CDIM  256   // embedding dim / K of the GEMM
#define HDIM  64
#define WDIM  64
#define NQ    65536   // BATCH*HDIM*WDIM
#define NE    1024    // codebook size
#define BM    32      // queries per block in argmin kernel

// d_out layout (floats): [0]=loss, [1..16777216]=z_q_st, [16777217..16842752]=idx, [16842753]=perplexity
#define ZQ_OFF   1
#define IDX_OFF  16777217
#define PERP_OFF 16842753

// ws layout: ee float[1024] @0 ; hist int[1024] @4096 ; loss_part double[256] @8192
#define WS_EE_OFF    0
#define WS_HIST_OFF  4096
#define WS_LOSS_OFF  8192

// ---- numpy-pairwise sum-of-squares over 128 contiguous floats (8-accumulator tree) ----
__device__ __forceinline__ float pw128_sq(const float* __restrict__ p) {
    float r[8];
#pragma unroll
    for (int j = 0; j < 8; j++) r[j] = __fmul_rn(p[j], p[j]);
#pragma unroll
    for (int i = 8; i < 128; i += 8) {
#pragma unroll
        for (int j = 0; j < 8; j++) r[j] = __fadd_rn(r[j], __fmul_rn(p[i + j], p[i + j]));
    }
    return __fadd_rn(__fadd_rn(__fadd_rn(r[0], r[1]), __fadd_rn(r[2], r[3])),
                     __fadd_rn(__fadd_rn(r[4], r[5]), __fadd_rn(r[6], r[7])));
}

// ---- k1: codebook norms (numpy-pairwise), zero hist + loss accumulators ----
__global__ void vq_prep(const float* __restrict__ W, float* __restrict__ ee,
                        int* __restrict__ hist, double* __restrict__ loss_part) {
    int t = blockIdx.x * 256 + threadIdx.x;   // 0..1023, grid=4
    hist[t] = 0;
    if (t < 256) loss_part[t] = 0.0;
    const float* p = W + (size_t)t * CDIM;
    ee[t] = __fadd_rn(pw128_sq(p), pw128_sq(p + 128));
}

// ---- k2: fused distance GEMM + argmin ----
__global__ __launch_bounds__(256, 2)
void vq_argmin(const float* __restrict__ z, const float* __restrict__ W,
               const float* __restrict__ ee, float* __restrict__ out_idx,
               int* __restrict__ hist) {
    __shared__ float A[CDIM][BM];       // 32 KB, k-major: A[c][q]
    __shared__ float zz_s[BM];
    __shared__ float tmp2[64];
    __shared__ float redD[BM][64];      // 8 KB
    __shared__ int   redI[BM][64];      // 8 KB
    __shared__ float pD[BM][8];
    __shared__ int   pI[BM][8];

    const int t   = threadIdx.x;
    const int n0  = blockIdx.x * BM;
    const int b   = n0 >> 12;
    const int h   = (n0 >> 6) & 63;
    const int w0  = n0 & 63;           // 0 or 32

    // ---- stage A: zf_tile[c][q] = z[b, c, h, w0+q]; coalesced float4 ----
    const float* zb = z + (size_t)b * (CDIM * HDIM * WDIM) + (size_t)h * WDIM + w0;
#pragma unroll
    for (int v = 0; v < 8; v++) {
        int idx4 = v * 256 + t;        // 0..2047
        int c  = idx4 >> 3;            // 8 float4 per 32-wide row
        int w4 = idx4 & 7;
        float4 val = *(const float4*)(zb + (size_t)c * (HDIM * WDIM) + w4 * 4);
        *(float4*)(&A[c][w4 * 4]) = val;
    }
    __syncthreads();

    // ---- zz per query, replicating numpy pairwise (two 128-blocks, 8 accumulators) ----
    if (t < 64) {
        int q = t >> 1, base = (t & 1) * 128;
        float r[8];
#pragma unroll
        for (int j = 0; j < 8; j++) { float x = A[base + j][q]; r[j] = __fmul_rn(x, x); }
        for (int i = 8; i < 128; i += 8) {
#pragma unroll
            for (int j = 0; j < 8; j++) { float x = A[base + i + j][q]; r[j] = __fadd_rn(r[j], __fmul_rn(x, x)); }
        }
        tmp2[t] = __fadd_rn(__fadd_rn(__fadd_rn(r[0], r[1]), __fadd_rn(r[2], r[3])),
                            __fadd_rn(__fadd_rn(r[4], r[5]), __fadd_rn(r[6], r[7])));
    }
    __syncthreads();
    if (t < BM) zz_s[t] = __fadd_rn(tmp2[2 * t], tmp2[2 * t + 1]);
    __syncthreads();

    const int tx = t & 63;             // 0..63: codes
    const int ty = t >> 6;             // 0..3 : one wave per ty (A reads broadcast)
    const int q0 = ty * 8;

    float bestD[8]; int bestI[8];
#pragma unroll
    for (int i = 0; i < 8; i++) { bestD[i] = 3.0e38f; bestI[i] = 0; }

    for (int chunk = 0; chunk < 4; chunk++) {
        const int e0 = chunk * 256 + tx * 4;
        const float* Wr = W + (size_t)e0 * CDIM;
        float acc[8][4];
#pragma unroll
        for (int i = 0; i < 8; i++)
#pragma unroll
            for (int j = 0; j < 4; j++) acc[i][j] = 0.0f;

        float4 bq[4];
#pragma unroll
        for (int j = 0; j < 4; j++) bq[j] = *(const float4*)(Wr + (size_t)j * CDIM);

        for (int k = 0; k < CDIM; k += 4) {
            // prefetch next k-step of B (wraps on last iter; harmless)
            float4 bn[4];
            const int kn = (k + 4) & (CDIM - 1);
#pragma unroll
            for (int j = 0; j < 4; j++) bn[j] = *(const float4*)(Wr + (size_t)j * CDIM + kn);

            float bm[4][4];
#pragma unroll
            for (int j = 0; j < 4; j++) {
                bm[j][0] = bq[j].x; bm[j][1] = bq[j].y; bm[j][2] = bq[j].z; bm[j][3] = bq[j].w;
            }
#pragma unroll
            for (int kk = 0; kk < 4; kk++) {
                const float4 a0 = *(const float4*)(&A[k + kk][q0]);
                const float4 a1 = *(const float4*)(&A[k + kk][q0 + 4]);
                float av[8] = {a0.x, a0.y, a0.z, a0.w, a1.x, a1.y, a1.z, a1.w};
#pragma unroll
                for (int i = 0; i < 8; i++)
#pragma unroll
                    for (int j = 0; j < 4; j++)
                        acc[i][j] = __fmaf_rn(av[i], bm[j][kk], acc[i][j]);
            }
#pragma unroll
            for (int j = 0; j < 4; j++) bq[j] = bn[j];
        }

        // epilogue: d = fl(fl(zz+ee) - 2m), running argmin (ascending e -> strict <)
        float4 ee4 = *(const float4*)(ee + e0);
        float eev[4] = {ee4.x, ee4.y, ee4.z, ee4.w};
#pragma unroll
        for (int i = 0; i < 8; i++) {
            float zzq = zz_s[q0 + i];
#pragma unroll
            for (int j = 0; j < 4; j++) {
                float s = __fadd_rn(zzq, eev[j]);
                float d = __fsub_rn(s, __fadd_rn(acc[i][j], acc[i][j]));
                if (d < bestD[i]) { bestD[i] = d; bestI[i] = e0 + j; }
            }
        }
    }

    // ---- cross-thread argmin reduce (lexicographic: min d, then min idx) ----
#pragma unroll
    for (int i = 0; i < 8; i++) { redD[q0 + i][tx] = bestD[i]; redI[q0 + i][tx] = bestI[i]; }
    __syncthreads();
    {
        int q = t >> 3, s = t & 7;
        float bd = redD[q][s * 8]; int bi = redI[q][s * 8];
#pragma unroll
        for (int u = 1; u < 8; u++) {
            float d2 = redD[q][s * 8 + u]; int i2 = redI[q][s * 8 + u];
            if (d2 < bd || (d2 == bd && i2 < bi)) { bd = d2; bi = i2; }
        }
        pD[q][s] = bd; pI[q][s] = bi;
    }
    __syncthreads();
    if (t < BM) {
        float bd = pD[t][0]; int bi = pI[t][0];
#pragma unroll
        for (int u = 1; u < 8; u++) {
            float d2 = pD[t][u]; int i2 = pI[t][u];
            if (d2 < bd || (d2 == bd && i2 < bi)) { bd = d2; bi = i2; }
        }
        out_idx[n0 + t] = (float)bi;
        atomicAdd(&hist[bi], 1);
    }
}

// ---- k4: gather z_q, straight-through output, loss partials ----
__global__ void vq_gather(const float* __restrict__ z, const float* __restrict__ W,
                          const float* __restrict__ idxf, float* __restrict__ zq_out,
                          double* __restrict__ loss_part) {
    const int gid = blockIdx.x * 256 + threadIdx.x;  // 0..4194303 (grid=16384)
    const int w4 = gid & 15;
    const int r  = gid >> 4;         // 0..262143
    const int h  = r & 63;
    const int c  = (r >> 6) & 255;
    const int b  = r >> 14;
    const size_t off = (((size_t)(b * CDIM + c) * HDIM + h) * WDIM) + w4 * 4;
    const float4 zp = *(const float4*)(z + off);
    const int n = b * 4096 + h * 64 + w4 * 4;

    float zpv[4] = {zp.x, zp.y, zp.z, zp.w};
    float ov[4];
    double ls = 0.0;
#pragma unroll
    for (int l = 0; l < 4; l++) {
        int idx = (int)idxf[n + l];
        float zq = W[(size_t)idx * CDIM + c];
        float t1 = __fsub_rn(zq, zpv[l]);       // fl(z_q - zp)
        ov[l] = __fadd_rn(zpv[l], t1);          // fl(zp + fl(z_q - zp))
        ls += (double)t1 * (double)t1;
    }
    float4 o = {ov[0], ov[1], ov[2], ov[3]};
    *(float4*)(zq_out + off) = o;

    // wave + block reduce, one atomic per block into 256 slots
#pragma unroll
    for (int s = 32; s > 0; s >>= 1) ls += __shfl_down(ls, s, 64);
    __shared__ double wsum[4];
    if ((threadIdx.x & 63) == 0) wsum[threadIdx.x >> 6] = ls;
    __syncthreads();
    if (threadIdx.x == 0) {
        double v = wsum[0] + wsum[1] + wsum[2] + wsum[3];
        atomicAdd(&loss_part[blockIdx.x & 255], v);
    }
}

// ---- k5: finalize loss + perplexity ----
__global__ void vq_final(const double* __restrict__ loss_part, const int* __restrict__ hist,
                         float* __restrict__ d_out) {
    __shared__ double s1[256], s2[256];
    const int t = threadIdx.x;
    double v = loss_part[t];
    double pv = 0.0;
#pragma unroll
    for (int j = 0; j < 4; j++) {
        int cnt = hist[t * 4 + j];
        double em = (double)cnt / 65536.0;
        pv += em * log(em + 1e-10);
    }
    s1[t] = v; s2[t] = pv;
    __syncthreads();
    for (int st = 128; st > 0; st >>= 1) {
        if (t < st) { s1[t] += s1[t + st]; s2[t] += s2[t + st]; }
        __syncthreads();
    }
    if (t == 0) {
        float m = (float)(s1[0] / 16777216.0);
        d_out[0] = 1.25f * m;                    // mean + 0.25*mean
        d_out[PERP_OFF] = (float)exp(-s2[0]);
    }
}

extern "C" void kernel_launch(void* const* d_in, const int* in_sizes, int n_in,
                              void* d_out, int out_size, void* d_ws, size_t ws_size,
                              hipStream_t stream) {
    const float* z = (const float*)d_in[0];
    const float* W = (const float*)d_in[1];
    float* out = (float*)d_out;

    float*  ee        = (float*)((char*)d_ws + WS_EE_OFF);
    int*    hist      = (int*)((char*)d_ws + WS_HIST_OFF);
    double* loss_part = (double*)((char*)d_ws + WS_LOSS_OFF);

    vq_prep<<<4, 256, 0, stream>>>(W, ee, hist, loss_part);
    vq_argmin<<<NQ / BM, 256, 0, stream>>>(z, W, ee, out + IDX_OFF, hist);
    vq_gather<<<(NQ * CDIM / 4) / 256, 256, 0, stream>>>(z, W, out + IDX_OFF, out + ZQ_OFF, loss_part);
    vq_final<<<1, 256, 0, stream>>>(loss_part, hist, out);
}

// Round 2
// 641.310 us; speedup vs baseline: 2.5448x; 2.5448x over previous
//
#include <hip/hip_runtime.h>
#include <hip/hip_bf16.h>

// Problem constants
#define BATCH 16
#define CDIM  256   // embedding dim / K of the GEMM
#define HDIM  64
#define WDIM  64
#define NQ    65536   // BATCH*HDIM*WDIM
#define NE    1024    // codebook size
#define BM    32      // queries per block in argmin kernel
#define KB    32      // k-chunk staged per B tile
#define BPAD  260     // Bs row stride: 16B-aligned, breaks 8-way write conflicts to 4-way

// d_out layout (floats): [0]=loss, [1..16777216]=z_q_st, [16777217..16842752]=idx, [16842753]=perplexity
#define ZQ_OFF   1
#define IDX_OFF  16777217
#define PERP_OFF 16842753

// ws layout: ee float[1024] @0 ; hist int[1024] @4096 ; loss_part double[256] @8192
#define WS_EE_OFF    0
#define WS_HIST_OFF  4096
#define WS_LOSS_OFF  8192

// ---- numpy-pairwise sum-of-squares over 128 contiguous floats (8-accumulator tree) ----
__device__ __forceinline__ float pw128_sq(const float* __restrict__ p) {
    float r[8];
#pragma unroll
    for (int j = 0; j < 8; j++) r[j] = __fmul_rn(p[j], p[j]);
#pragma unroll
    for (int i = 8; i < 128; i += 8) {
#pragma unroll
        for (int j = 0; j < 8; j++) r[j] = __fadd_rn(r[j], __fmul_rn(p[i + j], p[i + j]));
    }
    return __fadd_rn(__fadd_rn(__fadd_rn(r[0], r[1]), __fadd_rn(r[2], r[3])),
                     __fadd_rn(__fadd_rn(r[4], r[5]), __fadd_rn(r[6], r[7])));
}

// ---- k1: codebook norms (numpy-pairwise), zero hist + loss accumulators ----
__global__ void vq_prep(const float* __restrict__ W, float* __restrict__ ee,
                        int* __restrict__ hist, double* __restrict__ loss_part) {
    int t = blockIdx.x * 256 + threadIdx.x;   // 0..1023, grid=4
    hist[t] = 0;
    if (t < 256) loss_part[t] = 0.0;
    const float* p = W + (size_t)t * CDIM;
    ee[t] = __fadd_rn(pw128_sq(p), pw128_sq(p + 128));
}

// ---- k2: fused distance GEMM + argmin (B staged through LDS, coalesced) ----
__global__ __launch_bounds__(256, 2)
void vq_argmin(const float* __restrict__ z, const float* __restrict__ W,
               const float* __restrict__ ee, float* __restrict__ out_idx,
               int* __restrict__ hist) {
    __shared__ float A[CDIM][BM];       // 32 KB, k-major: A[c][q]
    __shared__ float Bs[KB][BPAD];      // 33.3 KB, k-major B tile
    __shared__ float zz_s[BM];
    __shared__ float tmp2[64];
    __shared__ float pD[BM][8];
    __shared__ int   pI[BM][8];
    // argmin reduction arrays alias A (A dead after main loop): 8 KB + 8 KB
    float (*redD)[64] = (float (*)[64])(&A[0][0]);
    int   (*redI)[64] = (int   (*)[64])(&A[64][0]);

    const int t   = threadIdx.x;
    const int n0  = blockIdx.x * BM;
    const int b   = n0 >> 12;
    const int h   = (n0 >> 6) & 63;
    const int w0  = n0 & 63;           // 0 or 32

    // ---- stage A: zf_tile[c][q] = z[b, c, h, w0+q]; coalesced float4 ----
    const float* zb = z + (size_t)b * (CDIM * HDIM * WDIM) + (size_t)h * WDIM + w0;
#pragma unroll
    for (int v = 0; v < 8; v++) {
        int idx4 = v * 256 + t;        // 0..2047
        int c  = idx4 >> 3;            // 8 float4 per 32-wide row
        int w4 = idx4 & 7;
        float4 val = *(const float4*)(zb + (size_t)c * (HDIM * WDIM) + w4 * 4);
        *(float4*)(&A[c][w4 * 4]) = val;
    }
    __syncthreads();

    // ---- zz per query, replicating numpy pairwise (two 128-blocks, 8 accumulators) ----
    if (t < 64) {
        int q = t >> 1, base = (t & 1) * 128;
        float r[8];
#pragma unroll
        for (int j = 0; j < 8; j++) { float x = A[base + j][q]; r[j] = __fmul_rn(x, x); }
        for (int i = 8; i < 128; i += 8) {
#pragma unroll
            for (int j = 0; j < 8; j++) { float x = A[base + i + j][q]; r[j] = __fadd_rn(r[j], __fmul_rn(x, x)); }
        }
        tmp2[t] = __fadd_rn(__fadd_rn(__fadd_rn(r[0], r[1]), __fadd_rn(r[2], r[3])),
                            __fadd_rn(__fadd_rn(r[4], r[5]), __fadd_rn(r[6], r[7])));
    }
    __syncthreads();
    if (t < BM) zz_s[t] = __fadd_rn(tmp2[2 * t], tmp2[2 * t + 1]);

    const int tx = t & 63;             // 0..63: codes (4 each)
    const int ty = t >> 6;             // 0..3 : query-group; A reads are wave-broadcast
    const int q0 = ty * 8;

    float bestD[8]; int bestI[8];
#pragma unroll
    for (int i = 0; i < 8; i++) { bestD[i] = 3.0e38f; bestI[i] = 0; }

    // B staging map: tile = 256 codes x 32 k. float4 id f = v*256+t:
    //   e = f>>3 (8 float4 per code-row), kq = f&7 -> k = kq*4..kq*4+3.
    // Global read: 8 consecutive lanes read 128 contiguous bytes of one W row.
    float4 breg[8];
    {
        // prefetch tile (ec=0, kc=0)
#pragma unroll
        for (int v = 0; v < 8; v++) {
            int f = v * 256 + t;
            int e = f >> 3, kq = f & 7;
            breg[v] = *(const float4*)(W + (size_t)e * CDIM + kq * 4);
        }
    }

    for (int ec = 0; ec < 4; ec++) {
        const int e0 = ec * 256 + tx * 4;
        float acc[8][4];
#pragma unroll
        for (int i = 0; i < 8; i++)
#pragma unroll
            for (int j = 0; j < 4; j++) acc[i][j] = 0.0f;

        for (int kc = 0; kc < 8; kc++) {
            __syncthreads();           // previous tile's compute done
            // write prefetched tile -> Bs (transpose to k-major)
#pragma unroll
            for (int v = 0; v < 8; v++) {
                int f = v * 256 + t;
                int e = f >> 3, kq = f & 7;
                Bs[kq * 4 + 0][e] = breg[v].x;
                Bs[kq * 4 + 1][e] = breg[v].y;
                Bs[kq * 4 + 2][e] = breg[v].z;
                Bs[kq * 4 + 3][e] = breg[v].w;
            }
            // prefetch next tile into registers
            int nkc = kc + 1, nec = ec;
            if (nkc == 8) { nkc = 0; nec++; }
            if (nec < 4) {
#pragma unroll
                for (int v = 0; v < 8; v++) {
                    int f = v * 256 + t;
                    int e = f >> 3, kq = f & 7;
                    breg[v] = *(const float4*)(W + (size_t)(nec * 256 + e) * CDIM + nkc * KB + kq * 4);
                }
            }
            __syncthreads();
            // compute KB k-steps; k-order over full loop is sequential 0..255 (bit-identical acc)
            const int kb = kc * KB;
#pragma unroll 4
            for (int k = 0; k < KB; k++) {
                const float4 b4 = *(const float4*)(&Bs[k][tx * 4]);
                const float4 a0 = *(const float4*)(&A[kb + k][q0]);
                const float4 a1 = *(const float4*)(&A[kb + k][q0 + 4]);
                float av[8] = {a0.x, a0.y, a0.z, a0.w, a1.x, a1.y, a1.z, a1.w};
                float bv[4] = {b4.x, b4.y, b4.z, b4.w};
#pragma unroll
                for (int i = 0; i < 8; i++)
#pragma unroll
                    for (int j = 0; j < 4; j++)
                        acc[i][j] = __fmaf_rn(av[i], bv[j], acc[i][j]);
            }
        }

        // epilogue: d = fl(fl(zz+ee) - 2m), running argmin (ascending e -> strict <)
        float4 ee4 = *(const float4*)(ee + e0);
        float eev[4] = {ee4.x, ee4.y, ee4.z, ee4.w};
#pragma unroll
        for (int i = 0; i < 8; i++) {
            float zzq = zz_s[q0 + i];
#pragma unroll
            for (int j = 0; j < 4; j++) {
                float s = __fadd_rn(zzq, eev[j]);
                float d = __fsub_rn(s, __fadd_rn(acc[i][j], acc[i][j]));
                if (d < bestD[i]) { bestD[i] = d; bestI[i] = e0 + j; }
            }
        }
    }

    // ---- cross-thread argmin reduce (lexicographic: min d, then min idx) ----
    __syncthreads();                   // A no longer read; reuse as redD/redI
#pragma unroll
    for (int i = 0; i < 8; i++) { redD[q0 + i][tx] = bestD[i]; redI[q0 + i][tx] = bestI[i]; }
    __syncthreads();
    {
        int q = t >> 3, s = t & 7;
        float bd = redD[q][s * 8]; int bi = redI[q][s * 8];
#pragma unroll
        for (int u = 1; u < 8; u++) {
            float d2 = redD[q][s * 8 + u]; int i2 = redI[q][s * 8 + u];
            if (d2 < bd || (d2 == bd && i2 < bi)) { bd = d2; bi = i2; }
        }
        pD[q][s] = bd; pI[q][s] = bi;
    }
    __syncthreads();
    if (t < BM) {
        float bd = pD[t][0]; int bi = pI[t][0];
#pragma unroll
        for (int u = 1; u < 8; u++) {
            float d2 = pD[t][u]; int i2 = pI[t][u];
            if (d2 < bd || (d2 == bd && i2 < bi)) { bd = d2; bi = i2; }
        }
        out_idx[n0 + t] = (float)bi;
        atomicAdd(&hist[bi], 1);
    }
}

// ---- k4: gather z_q, straight-through output, loss partials ----
__global__ void vq_gather(const float* __restrict__ z, const float* __restrict__ W,
                          const float* __restrict__ idxf, float* __restrict__ zq_out,
                          double* __restrict__ loss_part) {
    const int gid = blockIdx.x * 256 + threadIdx.x;  // 0..4194303 (grid=16384)
    const int w4 = gid & 15;
    const int r  = gid >> 4;         // 0..262143
    const int h  = r & 63;
    const int c  = (r >> 6) & 255;
    const int b  = r >> 14;
    const size_t off = (((size_t)(b * CDIM + c) * HDIM + h) * WDIM) + w4 * 4;
    const float4 zp = *(const float4*)(z + off);
    const int n = b * 4096 + h * 64 + w4 * 4;

    float zpv[4] = {zp.x, zp.y, zp.z, zp.w};
    float ov[4];
    double ls = 0.0;
#pragma unroll
    for (int l = 0; l < 4; l++) {
        int idx = (int)idxf[n + l];
        float zq = W[(size_t)idx * CDIM + c];
        float t1 = __fsub_rn(zq, zpv[l]);       // fl(z_q - zp)
        ov[l] = __fadd_rn(zpv[l], t1);          // fl(zp + fl(z_q - zp))
        ls += (double)t1 * (double)t1;
    }
    float4 o = {ov[0], ov[1], ov[2], ov[3]};
    *(float4*)(zq_out + off) = o;

    // wave + block reduce, one atomic per block into 256 slots
#pragma unroll
    for (int s = 32; s > 0; s >>= 1) ls += __shfl_down(ls, s, 64);
    __shared__ double wsum[4];
    if ((threadIdx.x & 63) == 0) wsum[threadIdx.x >> 6] = ls;
    __syncthreads();
    if (threadIdx.x == 0) {
        double v = wsum[0] + wsum[1] + wsum[2] + wsum[3];
        atomicAdd(&loss_part[blockIdx.x & 255], v);
    }
}

// ---- k5: finalize loss + perplexity ----
__global__ void vq_final(const double* __restrict__ loss_part, const int* __restrict__ hist,
                         float* __restrict__ d_out) {
    __shared__ double s1[256], s2[256];
    const int t = threadIdx.x;
    double v = loss_part[t];
    double pv = 0.0;
#pragma unroll
    for (int j = 0; j < 4; j++) {
        int cnt = hist[t * 4 + j];
        double em = (double)cnt / 65536.0;
        pv += em * log(em + 1e-10);
    }
    s1[t] = v; s2[t] = pv;
    __syncthreads();
    for (int st = 128; st > 0; st >>= 1) {
        if (t < st) { s1[t] += s1[t + st]; s2[t] += s2[t + st]; }
        __syncthreads();
    }
    if (t == 0) {
        float m = (float)(s1[0] / 16777216.0);
        d_out[0] = 1.25f * m;                    // mean + 0.25*mean
        d_out[PERP_OFF] = (float)exp(-s2[0]);
    }
}

extern "C" void kernel_launch(void* const* d_in, const int* in_sizes, int n_in,
                              void* d_out, int out_size, void* d_ws, size_t ws_size,
                              hipStream_t stream) {
    const float* z = (const float*)d_in[0];
    const float* W = (const float*)d_in[1];
    float* out = (float*)d_out;

    float*  ee        = (float*)((char*)d_ws + WS_EE_OFF);
    int*    hist      = (int*)((char*)d_ws + WS_HIST_OFF);
    double* loss_part = (double*)((char*)d_ws + WS_LOSS_OFF);

    vq_prep<<<4, 256, 0, stream>>>(W, ee, hist, loss_part);
    vq_argmin<<<NQ / BM, 256, 0, stream>>>(z, W, ee, out + IDX_OFF, hist);
    vq_gather<<<(NQ * CDIM / 4) / 256, 256, 0, stream>>>(z, W, out + IDX_OFF, out + ZQ_OFF, loss_part);
    vq_final<<<1, 256, 0, stream>>>(loss_part, hist, out);
}